// Round 12
// baseline (261.181 us; speedup 1.0000x reference)
//
#include <hip/hip_runtime.h>
#include <hip/hip_bf16.h>

// out[b,p,c] = sum_s x[b,s,c] * W[c,p,s] + bias[c,p]
// x: [64,720,321] f32, W: [321,720,720] f32, bias: [321,720] f32, out: [64,720,321] f32
// R12: A-in-LDS GEMM. Block = (channel, third-of-P), 4 waves. Whole-channel A
//      (64x720 bf16, 91KB padded) staged to LDS ONCE; each wave owns consecutive
//      BN=16 p-tiles with a PRIVATE quad-buffered B tile (4KB x 4), barrier-free
//      per-wave counted-vmcnt pipeline (wait vmcnt(12), stage m+4). Path bytes:
//      W 666MB + A 89MB = 755MB (vs R11 936, R5 1110) at R5's 4-waves/CU regime.
//      LDS 158.7KB -> 1 block/CU. Grid 321x3 = 963.

#define SEQ   720
#define PRED  720
#define CH    321
#define BATCH 64
#define RTOT  (BATCH*SEQ)
#define PBLK  240               /* P rows per block */
#define TPB   15                /* 16-wide tiles per block */
#define BPC   3                 /* blocks per channel */
#define BN    144               /* legacy fallback tiling */
#define NCHUNK 21
#define NGROUP (NCHUNK*5)

typedef __attribute__((ext_vector_type(8))) short short8;
typedef __attribute__((ext_vector_type(4))) float f32x4;
typedef __attribute__((ext_vector_type(4))) unsigned short us4;
typedef unsigned int u32;

__device__ __forceinline__ short bf16bits(float f) {
    return __builtin_bit_cast(short, __float2bfloat16(f));
}

// async global->LDS DMA, 16B/lane. LDS dest = wave-uniform base (+lane*16 by HW);
// global src is per-lane.
__device__ __forceinline__ void gload16(const void* g, void* l) {
    __builtin_amdgcn_global_load_lds((const __attribute__((address_space(1))) u32*)g,
                                     (__attribute__((address_space(3))) u32*)l, 16, 0, 0);
}

// ---------------- x transpose: [46080][321] f32 -> [321][46080] bf16 ----------------
__global__ __launch_bounds__(256) void xpose_kernel(const float* __restrict__ x,
                                                    unsigned short* __restrict__ xt) {
    __shared__ float tile[64][33];
    const int bid = blockIdx.x;
    const int rt = bid % (RTOT/64);
    const int ct = bid / (RTOT/64);
    const int r0 = rt*64, c0 = ct*32;
    const int t  = threadIdx.x;
    const int cl = t & 31, rl0 = t >> 5;
    const int cg = c0 + cl;
    if (cg < CH) {
#pragma unroll
        for (int j = 0; j < 8; ++j) {
            int rl = rl0 + j*8;
            tile[rl][cl] = x[(size_t)(r0+rl)*CH + cg];
        }
    }
    __syncthreads();
#pragma unroll
    for (int j = 0; j < 8; ++j) {
        int idx = t + j*256;
        int c_l = idx >> 6;
        int r_l = idx & 63;
        if (c0 + c_l < CH)
            xt[(size_t)(c0+c_l)*RTOT + r0 + r_l] = (unsigned short)bf16bits(tile[r_l][c_l]);
    }
}

// ---------------- A-in-LDS GEMM ----------------
// A LDS: [64 rows][91 x 16B chunks] bf16 (90 real chunks = 720 el + 1 pad chunk),
//        row stride 1456B (bank-spread: 12*r mod 32, 2-way max). Staged once, 91 DMAs.
// B LDS per wave: [4 bufs][16 rows][16 x 16B chunks] f32, phys chunk = logical^row.
// Per wave: tiles t0..t0+nt-1 (4/4/4/3), steps m=0..nt*12-1 (k=m%12, buf=m%4).
// K: 11 full BK=64 steps + tail of 16 (kch>=2 zeroed; A tail chunk clamped to <=89).
template<bool STAGED>
__global__ __launch_bounds__(256) void gemm_alds_kernel(
        const float* __restrict__ W, const float* __restrict__ bias,
        const unsigned short* __restrict__ xt, void* __restrict__ outp) {
    __shared__ __align__(16) unsigned short Ash[64*728];   // 93,184 B
    __shared__ __align__(16) float Bsh[4][4][16*64];       // 65,536 B (total 158,720)

    const int bid  = blockIdx.x;
    const int c    = bid / BPC;
    const int pb   = bid % BPC;
    const int blkP0 = pb * PBLK;
    const int tid  = threadIdx.x;
    const int w    = tid >> 6;
    const int lane = tid & 63;
    const int row  = lane & 15, kch = lane >> 4;

    const float* Wc          = W  + (size_t)c * ((size_t)PRED * SEQ);
    const unsigned short* Xc = xt + (size_t)c * RTOT;

    const int t0 = w * 4;                  // wave3: tiles 12..14
    const int nt = (w < 3) ? 4 : 3;
    const int M  = nt * 12;

    // ---- A stage: 91 DMAs total, distributed 23/23/23/22 ----
    {
        const int nd = (w < 3) ? 23 : 22;
        for (int i = 0; i < nd; ++i) {
            const int d   = w * 23 + i;
            const int o16 = d * 64 + lane;         // 16B-chunk id in padded layout
            int r = o16 / 91;
            int q = o16 - r * 91;                  // chunk in row, 0..90
            if (q > 89) q = 89;                    // pad chunk: clamp (never read)
            gload16(Xc + (size_t)r * SEQ + q * 8, &Ash[(size_t)d * 512]);
        }
    }

    // ---- B stage: 4 DMAs for step m (tile t0+m/12, k=m%12) into private buf m&3 ----
    auto stageB = [&](int m) {
        const int t  = t0 + m / 12;
        const int k  = m % 12;
        const int p0 = blkP0 + t * 16;
        float* dst = &Bsh[w][m & 3][0];
#pragma unroll
        for (int i = 0; i < 4; ++i) {
            const int r = 4*i + (lane >> 4);
            int sc = (lane & 15) ^ r;              // r < 16
            if (k == 11) sc &= 3;                  // tail: clamp into s<720 (finite dup)
            gload16(Wc + (size_t)(p0 + r)*SEQ + k*64 + sc*4, dst + i*256);
        }
    };

    f32x4 acc[4] = {};

    auto compute = [&](int m) {
        const int k = m % 12;
        const float* Bb = &Bsh[w][m & 3][0];
        const int smax = (k == 11) ? 1 : 2;
        for (int s = 0; s < smax; ++s) {
            short8 Af[4];
            int g = k*8 + s*4 + kch;
            if (g > 89) g = 89;                    // tail kch>=2: finite data, x0 below
#pragma unroll
            for (int mi = 0; mi < 4; ++mi) {
                const int r2 = mi*16 + row;
                Af[mi] = *reinterpret_cast<const short8*>(&Ash[r2*728 + g*8]);
            }
            short8 Bf;
            {
                const int qlo = (s*8 + 2*kch)     ^ row;
                const int qhi = (s*8 + 2*kch + 1) ^ row;
                f32x4 lo = *reinterpret_cast<const f32x4*>(Bb + row*64 + qlo*4);
                f32x4 hi = *reinterpret_cast<const f32x4*>(Bb + row*64 + qhi*4);
                short8 v;
#pragma unroll
                for (int j = 0; j < 4; ++j) { v[j] = bf16bits(lo[j]); v[4+j] = bf16bits(hi[j]); }
                Bf = v;
            }
            if (k == 11 && kch >= 2) { short8 z = {}; Bf = z; }  // zero invalid K cols
#pragma unroll
            for (int mi = 0; mi < 4; ++mi)
                acc[mi] = __builtin_amdgcn_mfma_f32_16x16x32_bf16(Af[mi], Bf, acc[mi], 0, 0, 0);
        }
    };

    auto epilogue = [&](int t) {
        const int p     = blkP0 + t*16 + row;      // C/D map: col=lane&15
        const int rquad = lane >> 4;
        const float bv  = bias[(size_t)c*PRED + p];
        if (STAGED) {
            unsigned short* stg = (unsigned short*)outp;   // stage[c][p][b] bf16
#pragma unroll
            for (int mi = 0; mi < 4; ++mi) {
                us4 u;
#pragma unroll
                for (int r = 0; r < 4; ++r)
                    u[r] = (unsigned short)bf16bits(acc[mi][r] + bv);
                *reinterpret_cast<us4*>(
                    stg + ((size_t)c*PRED + p)*BATCH + mi*16 + rquad*4) = u;
            }
        } else {
            float* outf = (float*)outp;
#pragma unroll
            for (int mi = 0; mi < 4; ++mi)
#pragma unroll
                for (int r = 0; r < 4; ++r) {
                    const int b = mi*16 + rquad*4 + r;
                    outf[((size_t)b*PRED + p)*CH + c] = acc[mi][r] + bv;
                }
        }
#pragma unroll
        for (int mi = 0; mi < 4; ++mi) acc[mi] = f32x4{0.f, 0.f, 0.f, 0.f};
    };

    // prologue: 4 B groups behind the A stage; wait A (16 = 4 B groups outstanding)
    stageB(0); stageB(1); stageB(2); stageB(3);
    asm volatile("s_waitcnt vmcnt(16)" ::: "memory");   // own A complete
    __builtin_amdgcn_sched_barrier(0);
    __builtin_amdgcn_s_barrier();                       // all waves' A complete

    for (int m = 0; m < M; ++m) {
        // tiered counted wait: stage(m) done, up to 3 newer groups stay in flight
        if      (m + 3 < M) { asm volatile("s_waitcnt vmcnt(12)" ::: "memory"); }
        else if (m + 2 < M) { asm volatile("s_waitcnt vmcnt(8)"  ::: "memory"); }
        else if (m + 1 < M) { asm volatile("s_waitcnt vmcnt(4)"  ::: "memory"); }
        else                { asm volatile("s_waitcnt vmcnt(0)"  ::: "memory"); }
        __builtin_amdgcn_sched_barrier(0);
        compute(m);
        asm volatile("s_waitcnt lgkmcnt(0)" ::: "memory");   // my reads of buf done
        __builtin_amdgcn_sched_barrier(0);
        if (m + 4 < M) stageB(m + 4);                   // refill just-freed buffer
        if ((m % 12) == 11) epilogue(t0 + m / 12);      // stores newest in FIFO
    }
}

// ---------------- fallback (no workspace): gather x directly, scattered stores ----------------
__global__ __launch_bounds__(192) void gemm_fallback_kernel(
        const float* __restrict__ W, const float* __restrict__ bias,
        const float* __restrict__ x, float* __restrict__ outp) {
    const int bid  = blockIdx.x;
    const int g    = (bid & 7) + 8*((bid >> 3) >> 4);
    const int coff = (bid >> 3) & 15;
    if (g >= NGROUP) return;
    const int c  = (g % NCHUNK)*16 + coff;
    if (c >= CH) return;
    const int p0 = (g / NCHUNK) * BN;
    const int tid = threadIdx.x, wv = tid >> 6, lane = tid & 63;
    const int row = lane & 15, kch = lane >> 4, nb = p0 + wv*48;
    const float* Wc = W + (size_t)c * ((size_t)PRED * SEQ);
    f32x4 acc[4][3] = {};
    for (int k = 0; k < 23; ++k) {
        const int kc = (k == 22) ? (kch & 1) : kch;
        const int s  = k*32 + kc*8;
        short8 Af[4], Bf[3];
#pragma unroll
        for (int mi = 0; mi < 4; ++mi) {
            short8 v;
#pragma unroll
            for (int j = 0; j < 8; ++j)
                v[j] = bf16bits(x[((size_t)(mi*16 + row)*SEQ + s + j)*CH + c]);
            Af[mi] = v;
        }
#pragma unroll
        for (int ni = 0; ni < 3; ++ni) {
            const float* p = Wc + (size_t)(nb + ni*16 + row)*SEQ + s;
            short8 v;
#pragma unroll
            for (int j = 0; j < 4; ++j) { v[j] = bf16bits(p[j]); v[4+j] = bf16bits(p[4+j]); }
            Bf[ni] = v;
        }
        if (k == 22 && kch >= 2) { short8 z = {}; Bf[0] = z; Bf[1] = z; Bf[2] = z; }
#pragma unroll
        for (int mi = 0; mi < 4; ++mi)
#pragma unroll
            for (int ni = 0; ni < 3; ++ni)
                acc[mi][ni] = __builtin_amdgcn_mfma_f32_16x16x32_bf16(
                                  Af[mi], Bf[ni], acc[mi][ni], 0, 0, 0);
    }
    const int col = lane & 15, rquad = lane >> 4;
#pragma unroll
    for (int ni = 0; ni < 3; ++ni) {
        const int p = nb + ni*16 + col;
        const float bv = bias[(size_t)c*PRED + p];
#pragma unroll
        for (int mi = 0; mi < 4; ++mi)
#pragma unroll
            for (int r = 0; r < 4; ++r)
                outp[((size_t)(mi*16 + rquad*4 + r)*PRED + p)*CH + c] = acc[mi][ni][r] + bv;
    }
}

// ---------------- unstage: stage[C][P][B] bf16 -> out[B][P][C] f32 ----------------
__global__ __launch_bounds__(256) void unstage_kernel(const unsigned short* __restrict__ stage,
                                                      float* __restrict__ out) {
    const int p  = blockIdx.x;
    const int c0 = blockIdx.y * 128;
    const int cn = (CH - c0 < 128) ? (CH - c0) : 128;
    __shared__ float tl[128][65];
    const int t = threadIdx.x;
    {
        const int b4  = (t & 15) * 4;      // 4 consecutive b per lane (us4, 8B)
        const int ci0 = t >> 4;            // 16 ci per pass
        for (int ci = ci0; ci < cn; ci += 16) {
            us4 u = *reinterpret_cast<const us4*>(
                        stage + ((size_t)(c0+ci)*PRED + p)*BATCH + b4);
#pragma unroll
            for (int j = 0; j < 4; ++j)
                tl[ci][b4+j] = __builtin_bit_cast(float, (u32)u[j] << 16);
        }
    }
    __syncthreads();
    {
        const int cl = t & 127;
        const int b0 = t >> 7;
        if (cl < cn)
#pragma unroll
            for (int bb = b0; bb < BATCH; bb += 2)
                out[((size_t)bb*PRED + p)*CH + c0 + cl] = tl[cl][bb];
    }
}

extern "C" void kernel_launch(void* const* d_in, const int* in_sizes, int n_in,
                              void* d_out, int out_size, void* d_ws, size_t ws_size,
                              hipStream_t stream) {
    const float* x    = (const float*)d_in[0];
    const float* W    = (const float*)d_in[1];
    const float* bias = (const float*)d_in[2];
    float* out        = (float*)d_out;

    const size_t xt_bytes    = (size_t)CH * RTOT * sizeof(unsigned short);        // 29.6 MB
    const size_t stage_bytes = (size_t)CH * PRED * BATCH * sizeof(unsigned short);// 29.6 MB

    if (ws_size >= xt_bytes + stage_bytes) {
        unsigned short* xtp = (unsigned short*)d_ws;
        unsigned short* stg = (unsigned short*)((char*)d_ws + xt_bytes);
        xpose_kernel<<<dim3((RTOT/64) * 11), dim3(256), 0, stream>>>(x, xtp);
        gemm_alds_kernel<true><<<dim3(CH * BPC), dim3(256), 0, stream>>>(W, bias, xtp, stg);
        unstage_kernel<<<dim3(PRED, 3), dim3(256), 0, stream>>>(stg, out);
    } else if (ws_size >= xt_bytes) {
        unsigned short* xtp = (unsigned short*)d_ws;
        xpose_kernel<<<dim3((RTOT/64) * 11), dim3(256), 0, stream>>>(x, xtp);
        gemm_alds_kernel<false><<<dim3(CH * BPC), dim3(256), 0, stream>>>(W, bias, xtp, out);
    } else {
        gemm_fallback_kernel<<<dim3(8 * 14 * 16), dim3(192), 0, stream>>>(
            W, bias, x, out);
    }
}

// Round 13
// 237.177 us; speedup vs baseline: 1.1012x; 1.1012x over previous
//
#include <hip/hip_runtime.h>
#include <hip/hip_bf16.h>

// out[b,p,c] = sum_s x[b,s,c] * W[c,p,s] + bias[c,p]
// x: [64,720,321] f32, W: [321,720,720] f32, bias: [321,720] f32, out: [64,720,321] f32
// R13: OCCUPANCY probe at the proven R5 structure. Identical barrier-free 1-wave
//      counted-vmcnt pipeline; BK 64->32 shrinks LDS 40->20KB => 8 blocks/CU
//      (2 waves/SIMD, 2x R5). Per K-step: 6 B-DMAs + 4 A-DMAs, vmcnt(10) steady.
//      K = 22 full steps + tail 16. Staged bf16 output + unstage kept.

#define SEQ   720
#define PRED  720
#define CH    321
#define BATCH 64
#define RTOT  (BATCH*SEQ)
#define BN1   48
#define NT1   15                /* 720/48 p-tiles */
#define BN    144               /* legacy fallback tiling */
#define NCHUNK 21
#define NGROUP (NCHUNK*5)

typedef __attribute__((ext_vector_type(8))) short short8;
typedef __attribute__((ext_vector_type(4))) float f32x4;
typedef __attribute__((ext_vector_type(4))) unsigned short us4;
typedef unsigned int u32;

__device__ __forceinline__ short bf16bits(float f) {
    return __builtin_bit_cast(short, __float2bfloat16(f));
}

// async global->LDS DMA, 16B/lane. LDS dest = wave-uniform base (+lane*16 by HW);
// global src is per-lane.
__device__ __forceinline__ void gload16(const void* g, void* l) {
    __builtin_amdgcn_global_load_lds((const __attribute__((address_space(1))) u32*)g,
                                     (__attribute__((address_space(3))) u32*)l, 16, 0, 0);
}

// ---------------- x transpose: [46080][321] f32 -> [321][46080] bf16 ----------------
__global__ __launch_bounds__(256) void xpose_kernel(const float* __restrict__ x,
                                                    unsigned short* __restrict__ xt) {
    __shared__ float tile[64][33];
    const int bid = blockIdx.x;
    const int rt = bid % (RTOT/64);
    const int ct = bid / (RTOT/64);
    const int r0 = rt*64, c0 = ct*32;
    const int t  = threadIdx.x;
    const int cl = t & 31, rl0 = t >> 5;
    const int cg = c0 + cl;
    if (cg < CH) {
#pragma unroll
        for (int j = 0; j < 8; ++j) {
            int rl = rl0 + j*8;
            tile[rl][cl] = x[(size_t)(r0+rl)*CH + cg];
        }
    }
    __syncthreads();
#pragma unroll
    for (int j = 0; j < 8; ++j) {
        int idx = t + j*256;
        int c_l = idx >> 6;
        int r_l = idx & 63;
        if (c0 + c_l < CH)
            xt[(size_t)(c0+c_l)*RTOT + r0 + r_l] = (unsigned short)bf16bits(tile[r_l][c_l]);
    }
}

// ---------------- per-channel GEMM: 1 wave/block, BK=32, 8 blocks/CU ----------------
// LDS B: [48 rows][8 x 16B chunks] f32, phys chunk q of row r = logical q^(r&7).
// LDS A: [64 rows][4 x 16B chunks] bf16, phys chunk q of row r = logical q^(r&3).
// Stage = 6 B-DMAs (8 rows x 128B) + 4 A-DMAs (16 rows x 64B) per K-step.
// K: 22 full BK=32 steps + tail of 16 (clamped sources, kch>=2 B-frags zeroed).
template<bool STAGED>
__global__ __launch_bounds__(64) void gemm1w_kernel(
        const float* __restrict__ W, const float* __restrict__ bias,
        const unsigned short* __restrict__ xt, void* __restrict__ outp) {
    __shared__ __align__(16) float          Bl[2][BN1*32];   // 2 x 6 KB
    __shared__ __align__(16) unsigned short Al[2][64*32];    // 2 x 4 KB (total 20 KB)

    const int bid = blockIdx.x;
    const int c   = bid / NT1;
    const int pt  = bid % NT1;
    const int p0  = pt * BN1;
    const int lane = threadIdx.x & 63;
    const int row = lane & 15, kch = lane >> 4;

    const float* Wc          = W  + (size_t)c * ((size_t)PRED * SEQ);
    const unsigned short* Xc = xt + (size_t)c * RTOT;

    auto stage = [&](int buf, int kk) {
        const bool tail = (kk == 22);
#pragma unroll
        for (int i = 0; i < 6; ++i) {               // B: rows 8i..8i+7, 128B each
            const int r = 8*i + (lane >> 3);
            int sc = (lane & 7) ^ (r & 7);
            if (tail) sc &= 3;                      // clamp into s<720 (finite dup)
            gload16(Wc + (size_t)(p0 + r)*SEQ + kk*32 + sc*4, &Bl[buf][i*256]);
        }
#pragma unroll
        for (int i = 0; i < 4; ++i) {               // A: rows 16i..16i+15, 64B each
            const int r = 16*i + (lane >> 2);
            int sc = (lane & 3) ^ (r & 3);
            if (tail) sc &= 1;
            gload16(Xc + (size_t)r*SEQ + kk*32 + sc*8, &Al[buf][i*512]);
        }
    };

    f32x4 acc[4][3] = {};

    auto compute = [&](int buf, bool ztail) {
        short8 Af[4];
#pragma unroll
        for (int mi = 0; mi < 4; ++mi) {
            const int r2 = mi*16 + row;
            const int qa = kch ^ (r2 & 3);
            Af[mi] = *reinterpret_cast<const short8*>(&Al[buf][r2*32 + qa*8]);
        }
        short8 Bf[3];
#pragma unroll
        for (int ni = 0; ni < 3; ++ni) {
            const int r2  = ni*16 + row;
            const int qlo = (2*kch)     ^ (r2 & 7);
            const int qhi = (2*kch + 1) ^ (r2 & 7);
            f32x4 lo = *reinterpret_cast<const f32x4*>(&Bl[buf][r2*32 + qlo*4]);
            f32x4 hi = *reinterpret_cast<const f32x4*>(&Bl[buf][r2*32 + qhi*4]);
            short8 v;
#pragma unroll
            for (int j = 0; j < 4; ++j) { v[j] = bf16bits(lo[j]); v[4+j] = bf16bits(hi[j]); }
            Bf[ni] = v;
        }
        if (ztail && kch >= 2) {       // zero invalid K range (clamped data is finite)
            short8 z = {};
            Bf[0] = z; Bf[1] = z; Bf[2] = z;
        }
#pragma unroll
        for (int mi = 0; mi < 4; ++mi)
#pragma unroll
            for (int ni = 0; ni < 3; ++ni)
                acc[mi][ni] = __builtin_amdgcn_mfma_f32_16x16x32_bf16(
                                  Af[mi], Bf[ni], acc[mi][ni], 0, 0, 0);
    };

    stage(0, 0);             // 10 outstanding
    stage(1, 1);             // 20 outstanding (< 63 vmcnt ceiling)
    for (int k = 0; k < 23; ++k) {
        const int buf = k & 1;
        if (k < 22) {
            // wait for stage(k)'s 10 DMAs; stage(k+1)'s 10 stay in flight
            asm volatile("s_waitcnt vmcnt(10)" ::: "memory");
        } else {
            asm volatile("s_waitcnt vmcnt(0)" ::: "memory");
        }
        __builtin_amdgcn_sched_barrier(0);
        compute(buf, k == 22);
        if (k <= 20) {
            asm volatile("s_waitcnt lgkmcnt(0)" ::: "memory");   // my reads of buf done
            __builtin_amdgcn_sched_barrier(0);
            stage(buf, k + 2);                       // refill just-freed buffer
        }
    }

    // Epilogue. C/D map: col = lane&15, row = (lane>>4)*4 + reg.
    const int col   = lane & 15;
    const int rquad = lane >> 4;
    if (STAGED) {
        unsigned short* stg = (unsigned short*)outp;  // stage[c][p][b] bf16
#pragma unroll
        for (int ni = 0; ni < 3; ++ni) {
            const int p = p0 + ni*16 + col;
            const float bv = bias[(size_t)c*PRED + p];
#pragma unroll
            for (int mi = 0; mi < 4; ++mi) {
                us4 u;
#pragma unroll
                for (int r = 0; r < 4; ++r)
                    u[r] = (unsigned short)bf16bits(acc[mi][ni][r] + bv);
                *reinterpret_cast<us4*>(
                    stg + ((size_t)c*PRED + p)*BATCH + mi*16 + rquad*4) = u;
            }
        }
    } else {
        float* outf = (float*)outp;
#pragma unroll
        for (int ni = 0; ni < 3; ++ni) {
            const int p = p0 + ni*16 + col;
            const float bv = bias[(size_t)c*PRED + p];
#pragma unroll
            for (int mi = 0; mi < 4; ++mi)
#pragma unroll
                for (int r = 0; r < 4; ++r) {
                    const int b = mi*16 + rquad*4 + r;
                    outf[((size_t)b*PRED + p)*CH + c] = acc[mi][ni][r] + bv;
                }
        }
    }
}

// ---------------- fallback (no workspace): gather x directly, scattered stores ----------------
__global__ __launch_bounds__(192) void gemm_fallback_kernel(
        const float* __restrict__ W, const float* __restrict__ bias,
        const float* __restrict__ x, float* __restrict__ outp) {
    const int bid  = blockIdx.x;
    const int g    = (bid & 7) + 8*((bid >> 3) >> 4);
    const int coff = (bid >> 3) & 15;
    if (g >= NGROUP) return;
    const int c  = (g % NCHUNK)*16 + coff;
    if (c >= CH) return;
    const int p0 = (g / NCHUNK) * BN;
    const int tid = threadIdx.x, wv = tid >> 6, lane = tid & 63;
    const int row = lane & 15, kch = lane >> 4, nb = p0 + wv*48;
    const float* Wc = W + (size_t)c * ((size_t)PRED * SEQ);
    f32x4 acc[4][3] = {};
    for (int k = 0; k < 23; ++k) {
        const int kc = (k == 22) ? (kch & 1) : kch;
        const int s  = k*32 + kc*8;
        short8 Af[4], Bf[3];
#pragma unroll
        for (int mi = 0; mi < 4; ++mi) {
            short8 v;
#pragma unroll
            for (int j = 0; j < 8; ++j)
                v[j] = bf16bits(x[((size_t)(mi*16 + row)*SEQ + s + j)*CH + c]);
            Af[mi] = v;
        }
#pragma unroll
        for (int ni = 0; ni < 3; ++ni) {
            const float* p = Wc + (size_t)(nb + ni*16 + row)*SEQ + s;
            short8 v;
#pragma unroll
            for (int j = 0; j < 4; ++j) { v[j] = bf16bits(p[j]); v[4+j] = bf16bits(p[4+j]); }
            Bf[ni] = v;
        }
        if (k == 22 && kch >= 2) { short8 z = {}; Bf[0] = z; Bf[1] = z; Bf[2] = z; }
#pragma unroll
        for (int mi = 0; mi < 4; ++mi)
#pragma unroll
            for (int ni = 0; ni < 3; ++ni)
                acc[mi][ni] = __builtin_amdgcn_mfma_f32_16x16x32_bf16(
                                  Af[mi], Bf[ni], acc[mi][ni], 0, 0, 0);
    }
    const int col = lane & 15, rquad = lane >> 4;
#pragma unroll
    for (int ni = 0; ni < 3; ++ni) {
        const int p = nb + ni*16 + col;
        const float bv = bias[(size_t)c*PRED + p];
#pragma unroll
        for (int mi = 0; mi < 4; ++mi)
#pragma unroll
            for (int r = 0; r < 4; ++r)
                outp[((size_t)(mi*16 + rquad*4 + r)*PRED + p)*CH + c] = acc[mi][ni][r] + bv;
    }
}

// ---------------- unstage: stage[C][P][B] bf16 -> out[B][P][C] f32 ----------------
__global__ __launch_bounds__(256) void unstage_kernel(const unsigned short* __restrict__ stage,
                                                      float* __restrict__ out) {
    const int p  = blockIdx.x;
    const int c0 = blockIdx.y * 128;
    const int cn = (CH - c0 < 128) ? (CH - c0) : 128;
    __shared__ float tl[128][65];
    const int t = threadIdx.x;
    {
        const int b4  = (t & 15) * 4;      // 4 consecutive b per lane (us4, 8B)
        const int ci0 = t >> 4;            // 16 ci per pass
        for (int ci = ci0; ci < cn; ci += 16) {
            us4 u = *reinterpret_cast<const us4*>(
                        stage + ((size_t)(c0+ci)*PRED + p)*BATCH + b4);
#pragma unroll
            for (int j = 0; j < 4; ++j)
                tl[ci][b4+j] = __builtin_bit_cast(float, (u32)u[j] << 16);
        }
    }
    __syncthreads();
    {
        const int cl = t & 127;
        const int b0 = t >> 7;
        if (cl < cn)
#pragma unroll
            for (int bb = b0; bb < BATCH; bb += 2)
                out[((size_t)bb*PRED + p)*CH + c0 + cl] = tl[cl][bb];
    }
}

extern "C" void kernel_launch(void* const* d_in, const int* in_sizes, int n_in,
                              void* d_out, int out_size, void* d_ws, size_t ws_size,
                              hipStream_t stream) {
    const float* x    = (const float*)d_in[0];
    const float* W    = (const float*)d_in[1];
    const float* bias = (const float*)d_in[2];
    float* out        = (float*)d_out;

    const size_t xt_bytes    = (size_t)CH * RTOT * sizeof(unsigned short);        // 29.6 MB
    const size_t stage_bytes = (size_t)CH * PRED * BATCH * sizeof(unsigned short);// 29.6 MB

    if (ws_size >= xt_bytes + stage_bytes) {
        unsigned short* xtp = (unsigned short*)d_ws;
        unsigned short* stg = (unsigned short*)((char*)d_ws + xt_bytes);
        xpose_kernel<<<dim3((RTOT/64) * 11), dim3(256), 0, stream>>>(x, xtp);
        gemm1w_kernel<true><<<dim3(CH * NT1), dim3(64), 0, stream>>>(W, bias, xtp, stg);
        unstage_kernel<<<dim3(PRED, 3), dim3(256), 0, stream>>>(stg, out);
    } else if (ws_size >= xt_bytes) {
        unsigned short* xtp = (unsigned short*)d_ws;
        xpose_kernel<<<dim3((RTOT/64) * 11), dim3(256), 0, stream>>>(x, xtp);
        gemm1w_kernel<false><<<dim3(CH * NT1), dim3(64), 0, stream>>>(W, bias, xtp, out);
    } else {
        gemm_fallback_kernel<<<dim3(8 * 14 * 16), dim3(192), 0, stream>>>(
            W, bias, x, out);
    }
}

// Round 14
// 214.277 us; speedup vs baseline: 1.2189x; 1.1069x over previous
//
#include <hip/hip_runtime.h>
#include <hip/hip_bf16.h>

// out[b,p,c] = sum_s x[b,s,c] * W[c,p,s] + bias[c,p]
// x: [64,720,321] f32, W: [321,720,720] f32, bias: [321,720] f32, out: [64,720,321] f32
// R14 = R11 verbatim (best measured: 214.9us). Final configuration.
//   - xpose: x -> xt[C][B][S] bf16 (coalesced GEMM A-loads)
//   - GEMM: 1-wave blocks, BN=80, BK=64, barrier-free counted-vmcnt double-buffer,
//     global_load_lds staging (256B bursts/W-row), XOR-swizzled LDS (0 conflicts),
//     bf16 MFMA 16x16x32. W read exactly once at the measured ~4.4 TB/s pattern
//     ceiling (R10 counters: MfmaUtil 5.9%, VALUBusy 13.6%, writes fully merged).
//   - staged bf16 output [C][P][B] + LDS-transpose unstage (write-amp fix, R1: 6x).

#define SEQ   720
#define PRED  720
#define CH    321
#define BATCH 64
#define RTOT  (BATCH*SEQ)
#define BNW   80
#define NTW   9                 /* 720/80 p-tiles */
#define BN    144               /* legacy fallback tiling */
#define NCHUNK 21
#define NGROUP (NCHUNK*5)

typedef __attribute__((ext_vector_type(8))) short short8;
typedef __attribute__((ext_vector_type(4))) float f32x4;
typedef __attribute__((ext_vector_type(4))) unsigned short us4;
typedef unsigned int u32;

__device__ __forceinline__ short bf16bits(float f) {
    return __builtin_bit_cast(short, __float2bfloat16(f));
}

// async global->LDS DMA, 16B/lane. LDS dest = wave-uniform base (+lane*16 by HW);
// global src is per-lane.
__device__ __forceinline__ void gload16(const void* g, void* l) {
    __builtin_amdgcn_global_load_lds((const __attribute__((address_space(1))) u32*)g,
                                     (__attribute__((address_space(3))) u32*)l, 16, 0, 0);
}

// ---------------- x transpose: [46080][321] f32 -> [321][46080] bf16 ----------------
__global__ __launch_bounds__(256) void xpose_kernel(const float* __restrict__ x,
                                                    unsigned short* __restrict__ xt) {
    __shared__ float tile[64][33];
    const int bid = blockIdx.x;
    const int rt = bid % (RTOT/64);
    const int ct = bid / (RTOT/64);
    const int r0 = rt*64, c0 = ct*32;
    const int t  = threadIdx.x;
    const int cl = t & 31, rl0 = t >> 5;
    const int cg = c0 + cl;
    if (cg < CH) {
#pragma unroll
        for (int j = 0; j < 8; ++j) {
            int rl = rl0 + j*8;
            tile[rl][cl] = x[(size_t)(r0+rl)*CH + cg];
        }
    }
    __syncthreads();
#pragma unroll
    for (int j = 0; j < 8; ++j) {
        int idx = t + j*256;
        int c_l = idx >> 6;
        int r_l = idx & 63;
        if (c0 + c_l < CH)
            xt[(size_t)(c0+c_l)*RTOT + r0 + r_l] = (unsigned short)bf16bits(tile[r_l][c_l]);
    }
}

// ---------------- per-channel GEMM: 1 wave/block, BN=80, BK=64, barrier-free ----------------
// LDS B: [80 rows][16 x 16B chunks] f32, phys chunk q of row r = logical q^(r&15).
// LDS A: [64 rows][8 x 16B chunks] bf16, phys chunk q of row r = logical q^(r&7).
// Stage = 20 B-DMAs + 8 A-DMAs per K-step (1KB each: 4 rows x 256B / 8 rows x 128B).
// K: 11 full BK=64 steps + tail of 16 (clamped sources, kch>=2 B-frags zeroed).
template<bool STAGED>
__global__ __launch_bounds__(64) void gemm1w_kernel(
        const float* __restrict__ W, const float* __restrict__ bias,
        const unsigned short* __restrict__ xt, void* __restrict__ outp) {
    __shared__ __align__(16) float          Bl[2][BNW*64];   // 2 x 20 KB
    __shared__ __align__(16) unsigned short Al[2][64*64];    // 2 x  8 KB (total 57.3KB)

    const int bid = blockIdx.x;
    const int c   = bid / NTW;
    const int pt  = bid % NTW;
    const int p0  = pt * BNW;
    const int lane = threadIdx.x & 63;
    const int row = lane & 15, kch = lane >> 4;

    const float* Wc          = W  + (size_t)c * ((size_t)PRED * SEQ);
    const unsigned short* Xc = xt + (size_t)c * RTOT;

    auto stage = [&](int buf, int kk) {
        const bool tail = (kk == 11);
#pragma unroll
        for (int i = 0; i < 20; ++i) {              // B: rows 4i..4i+3, 256B each
            const int r = 4*i + (lane >> 4);
            int sc = (lane & 15) ^ (r & 15);
            if (tail) sc &= 3;                      // clamp into s<720 (finite dup)
            gload16(Wc + (size_t)(p0 + r)*SEQ + kk*64 + sc*4, &Bl[buf][i*256]);
        }
#pragma unroll
        for (int i = 0; i < 8; ++i) {               // A: rows 8i..8i+7, 128B each
            const int r = 8*i + (lane >> 3);
            int sc = (lane & 7) ^ (r & 7);
            if (tail) sc &= 1;
            gload16(Xc + (size_t)r*SEQ + kk*64 + sc*8, &Al[buf][i*512]);
        }
    };

    f32x4 acc[4][5] = {};

    auto compute = [&](int buf, int s, bool ztail) {
        short8 Af[4];
#pragma unroll
        for (int mi = 0; mi < 4; ++mi) {
            const int r2 = mi*16 + row;
            const int qa = (s*4 + kch) ^ (r2 & 7);
            Af[mi] = *reinterpret_cast<const short8*>(&Al[buf][r2*64 + qa*8]);
        }
        short8 Bf[5];
#pragma unroll
        for (int ni = 0; ni < 5; ++ni) {
            const int r2  = ni*16 + row;
            const int qlo = (s*8 + 2*kch)     ^ (r2 & 15);
            const int qhi = (s*8 + 2*kch + 1) ^ (r2 & 15);
            f32x4 lo = *reinterpret_cast<const f32x4*>(&Bl[buf][r2*64 + qlo*4]);
            f32x4 hi = *reinterpret_cast<const f32x4*>(&Bl[buf][r2*64 + qhi*4]);
            short8 v;
#pragma unroll
            for (int j = 0; j < 4; ++j) { v[j] = bf16bits(lo[j]); v[4+j] = bf16bits(hi[j]); }
            Bf[ni] = v;
        }
        if (ztail && kch >= 2) {       // zero invalid K range (clamped data is finite)
            short8 z = {};
#pragma unroll
            for (int ni = 0; ni < 5; ++ni) Bf[ni] = z;
        }
#pragma unroll
        for (int mi = 0; mi < 4; ++mi)
#pragma unroll
            for (int ni = 0; ni < 5; ++ni)
                acc[mi][ni] = __builtin_amdgcn_mfma_f32_16x16x32_bf16(
                                  Af[mi], Bf[ni], acc[mi][ni], 0, 0, 0);
    };

    stage(0, 0);             // 28 outstanding
    stage(1, 1);             // 56 outstanding (< 63 vmcnt ceiling)
    for (int k = 0; k < 11; ++k) {
        const int buf = k & 1;
        // wait for stage(k)'s 28 DMAs; stage(k+1)'s 28 stay in flight
        asm volatile("s_waitcnt vmcnt(28)" ::: "memory");
        __builtin_amdgcn_sched_barrier(0);
        compute(buf, 0, false);
        compute(buf, 1, false);
        asm volatile("s_waitcnt lgkmcnt(0)" ::: "memory");   // my reads of buf done
        __builtin_amdgcn_sched_barrier(0);
        if (k <= 9) stage(buf, k + 2);               // refill just-freed buffer
    }
    {   // k=11 tail (16 cols), buf 1
        asm volatile("s_waitcnt vmcnt(0)" ::: "memory");
        __builtin_amdgcn_sched_barrier(0);
        compute(1, 0, true);
    }

    // Epilogue. C/D map: col = lane&15, row = (lane>>4)*4 + reg.
    const int col   = lane & 15;
    const int rquad = lane >> 4;
    if (STAGED) {
        unsigned short* stg = (unsigned short*)outp;  // stage[c][p][b] bf16
#pragma unroll
        for (int ni = 0; ni < 5; ++ni) {
            const int p = p0 + ni*16 + col;
            const float bv = bias[(size_t)c*PRED + p];
#pragma unroll
            for (int mi = 0; mi < 4; ++mi) {
                us4 u;
#pragma unroll
                for (int r = 0; r < 4; ++r)
                    u[r] = (unsigned short)bf16bits(acc[mi][ni][r] + bv);
                *reinterpret_cast<us4*>(
                    stg + ((size_t)c*PRED + p)*BATCH + mi*16 + rquad*4) = u;
            }
        }
    } else {
        float* outf = (float*)outp;
#pragma unroll
        for (int ni = 0; ni < 5; ++ni) {
            const int p = p0 + ni*16 + col;
            const float bv = bias[(size_t)c*PRED + p];
#pragma unroll
            for (int mi = 0; mi < 4; ++mi)
#pragma unroll
                for (int r = 0; r < 4; ++r) {
                    const int b = mi*16 + rquad*4 + r;
                    outf[((size_t)b*PRED + p)*CH + c] = acc[mi][ni][r] + bv;
                }
        }
    }
}

// ---------------- fallback (no workspace): gather x directly, scattered stores ----------------
__global__ __launch_bounds__(192) void gemm_fallback_kernel(
        const float* __restrict__ W, const float* __restrict__ bias,
        const float* __restrict__ x, float* __restrict__ outp) {
    const int bid  = blockIdx.x;
    const int g    = (bid & 7) + 8*((bid >> 3) >> 4);
    const int coff = (bid >> 3) & 15;
    if (g >= NGROUP) return;
    const int c  = (g % NCHUNK)*16 + coff;
    if (c >= CH) return;
    const int p0 = (g / NCHUNK) * BN;
    const int tid = threadIdx.x, wv = tid >> 6, lane = tid & 63;
    const int row = lane & 15, kch = lane >> 4, nb = p0 + wv*48;
    const float* Wc = W + (size_t)c * ((size_t)PRED * SEQ);
    f32x4 acc[4][3] = {};
    for (int k = 0; k < 23; ++k) {
        const int kc = (k == 22) ? (kch & 1) : kch;
        const int s  = k*32 + kc*8;
        short8 Af[4], Bf[3];
#pragma unroll
        for (int mi = 0; mi < 4; ++mi) {
            short8 v;
#pragma unroll
            for (int j = 0; j < 8; ++j)
                v[j] = bf16bits(x[((size_t)(mi*16 + row)*SEQ + s + j)*CH + c]);
            Af[mi] = v;
        }
#pragma unroll
        for (int ni = 0; ni < 3; ++ni) {
            const float* p = Wc + (size_t)(nb + ni*16 + row)*SEQ + s;
            short8 v;
#pragma unroll
            for (int j = 0; j < 4; ++j) { v[j] = bf16bits(p[j]); v[4+j] = bf16bits(p[4+j]); }
            Bf[ni] = v;
        }
        if (k == 22 && kch >= 2) { short8 z = {}; Bf[0] = z; Bf[1] = z; Bf[2] = z; }
#pragma unroll
        for (int mi = 0; mi < 4; ++mi)
#pragma unroll
            for (int ni = 0; ni < 3; ++ni)
                acc[mi][ni] = __builtin_amdgcn_mfma_f32_16x16x32_bf16(
                                  Af[mi], Bf[ni], acc[mi][ni], 0, 0, 0);
    }
    const int col = lane & 15, rquad = lane >> 4;
#pragma unroll
    for (int ni = 0; ni < 3; ++ni) {
        const int p = nb + ni*16 + col;
        const float bv = bias[(size_t)c*PRED + p];
#pragma unroll
        for (int mi = 0; mi < 4; ++mi)
#pragma unroll
            for (int r = 0; r < 4; ++r)
                outp[((size_t)(mi*16 + rquad*4 + r)*PRED + p)*CH + c] = acc[mi][ni][r] + bv;
    }
}

// ---------------- unstage: stage[C][P][B] bf16 -> out[B][P][C] f32 ----------------
__global__ __launch_bounds__(256) void unstage_kernel(const unsigned short* __restrict__ stage,
                                                      float* __restrict__ out) {
    const int p  = blockIdx.x;
    const int c0 = blockIdx.y * 128;
    const int cn = (CH - c0 < 128) ? (CH - c0) : 128;
    __shared__ float tl[128][65];
    const int t = threadIdx.x;
    {
        const int b4  = (t & 15) * 4;      // 4 consecutive b per lane (us4, 8B)
        const int ci0 = t >> 4;            // 16 ci per pass
        for (int ci = ci0; ci < cn; ci += 16) {
            us4 u = *reinterpret_cast<const us4*>(
                        stage + ((size_t)(c0+ci)*PRED + p)*BATCH + b4);
#pragma unroll
            for (int j = 0; j < 4; ++j)
                tl[ci][b4+j] = __builtin_bit_cast(float, (u32)u[j] << 16);
        }
    }
    __syncthreads();
    {
        const int cl = t & 127;
        const int b0 = t >> 7;
        if (cl < cn)
#pragma unroll
            for (int bb = b0; bb < BATCH; bb += 2)
                out[((size_t)bb*PRED + p)*CH + c0 + cl] = tl[cl][bb];
    }
}

extern "C" void kernel_launch(void* const* d_in, const int* in_sizes, int n_in,
                              void* d_out, int out_size, void* d_ws, size_t ws_size,
                              hipStream_t stream) {
    const float* x    = (const float*)d_in[0];
    const float* W    = (const float*)d_in[1];
    const float* bias = (const float*)d_in[2];
    float* out        = (float*)d_out;

    const size_t xt_bytes    = (size_t)CH * RTOT * sizeof(unsigned short);        // 29.6 MB
    const size_t stage_bytes = (size_t)CH * PRED * BATCH * sizeof(unsigned short);// 29.6 MB

    if (ws_size >= xt_bytes + stage_bytes) {
        unsigned short* xtp = (unsigned short*)d_ws;
        unsigned short* stg = (unsigned short*)((char*)d_ws + xt_bytes);
        xpose_kernel<<<dim3((RTOT/64) * 11), dim3(256), 0, stream>>>(x, xtp);
        gemm1w_kernel<true><<<dim3(CH * NTW), dim3(64), 0, stream>>>(W, bias, xtp, stg);
        unstage_kernel<<<dim3(PRED, 3), dim3(256), 0, stream>>>(stg, out);
    } else if (ws_size >= xt_bytes) {
        unsigned short* xtp = (unsigned short*)d_ws;
        xpose_kernel<<<dim3((RTOT/64) * 11), dim3(256), 0, stream>>>(x, xtp);
        gemm1w_kernel<false><<<dim3(CH * NTW), dim3(64), 0, stream>>>(W, bias, xtp, out);
    } else {
        gemm_fallback_kernel<<<dim3(8 * 14 * 16), dim3(192), 0, stream>>>(
            W, bias, x, out);
    }
}